// Round 1
// 115.991 us; speedup vs baseline: 1.0445x; 1.0445x over previous
//
#include <hip/hip_runtime.h>
#include <hip/hip_bf16.h>
#include <math.h>

#define NN 256
#define DD 128
#define EE 64
#define APAD 392   // kernel2 A row stride (ushorts)
#define RPAD 136   // kernel2 rbuf row stride (ushorts)

typedef __attribute__((ext_vector_type(8))) short short8;
typedef __attribute__((ext_vector_type(4))) float f32x4;

static __device__ __forceinline__ unsigned short f2bf(float f) {
    __hip_bfloat16 b = __float2bfloat16(f);
    return *reinterpret_cast<unsigned short*>(&b);
}

static __device__ __forceinline__ float sigm(float l) {
    return __fdividef(1.f, 1.f + __expf(-l));
}

// bf16 B-fragment for mfma_16x16x32 from row-major f32 B[K][128] in global.
static __device__ __forceinline__ short8 ldb(const float* __restrict__ B, int kbase, int d) {
    unsigned short tmp[8];
    #pragma unroll
    for (int j = 0; j < 8; ++j) tmp[j] = f2bf(B[(kbase + j) * DD + d]);
    return *(const short8*)tmp;
}

// ---------------- Kernel 1: gate + masked aggregation (+ u1t/u2t pack) -------
// R12 structure: cooperative LDS P-build (replaces the per-wave duplicated
// in-register A build of R10).  All 256 threads build P[16j][64e] ONCE per
// j-tile into an XOR-swizzled double-buffered LDS tile (16 fma + 1 b64 write
// per thread), then each wave ds_read_b128's its A fragments.  This removes
// the 4x wave duplication AND the qa/qb 64-VGPR register cache (which at
// VGPR_Count=64 was being rematerialized from LDS every tile anyway).
// Cost: one __syncthreads per tile, hidden by 8 resident blocks/CU.
// Per-lane live set SHRINKS (R7/R9 lesson: never grow it).
__global__ __launch_bounds__(256, 4)
void ecgc_gate(const float* __restrict__ h_g,
               const float* __restrict__ ef_g,
               const int*   __restrict__ mask_g,
               const float* __restrict__ W1_g,
               const float* __restrict__ b1_g,
               const float* __restrict__ W2_g,
               const float* __restrict__ b2_g,
               const float* __restrict__ U1_g,
               const float* __restrict__ U2_g,
               float*          __restrict__ aggf,
               unsigned short* __restrict__ u1t,
               unsigned short* __restrict__ u2t)
{
    const int bi   = blockIdx.x;
    const int t    = threadIdx.x;
    const int lane = t & 63;
    const int w    = t >> 6;
    const int m16  = lane & 15;
    const int quad = lane >> 4;
    // build-role indices: thread owns (j = bj, e = beb..beb+3)
    const int bj   = t & 15;
    const int beb  = (t >> 4) << 2;

    __shared__ __align__(16) float sh_ef4[NN * 4];   // 4 KB
    __shared__ __align__(16) float sh_q4[EE * 4];    // 1 KB {base,w10,w11,w12}
    __shared__ float sh_basep[4 * EE];               // 1 KB
    __shared__ float sh_w1e[3 * EE];
    __shared__ int   sh_jlist[NN], sh_wcnt[4], sh_cnt;
    __shared__ __align__(16) unsigned short sh_P[2][16 * EE];  // 4 KB dbuf, swizzled

    // ---- u1t/u2t bf16 pack slice: 65536 elems over 2048 blocks ----
    // New layout: frag-major [k>>3][d][k&7] so kernel2's B loads are 256-B
    // coalesced runs (old [d][k] layout was 768-B-strided 16-B loads).
    if (t < 32) {
        const int flat = bi * 32 + t;
        if (flat < 384 * DD) {
            const int d = flat / 384, k = flat - d * 384;
            u1t[((k >> 3) * DD + d) * 8 + (k & 7)] = f2bf(U1_g[k * DD + d]);
        } else {
            const int f2i = flat - 384 * DD;
            const int d = f2i >> 7, k = f2i & 127;
            u2t[((k >> 3) * DD + d) * 8 + (k & 7)] = f2bf(U2_g[k * DD + d]);
        }
    }

    // ---- stage ----
    {
        const float* efr = ef_g + (size_t)bi * NN * 3;
        sh_ef4[t * 4 + 0] = efr[t * 3 + 0];
        sh_ef4[t * 4 + 1] = efr[t * 3 + 1];
        sh_ef4[t * 4 + 2] = efr[t * 3 + 2];
        sh_ef4[t * 4 + 3] = 0.f;
    }
    if (t < 192) sh_w1e[t] = W1_g[(DD + (t >> 6)) * EE + (t & 63)];

    const int mk = (mask_g[bi * NN + t] != 0) ? 1 : 0;
    const unsigned long long bal = __ballot(mk);
    if (lane == 0) sh_wcnt[w] = __popcll(bal);
    const int pre = __popcll(bal & ((1ull << lane) - 1ull));

    // basep: thread (e = t&63) partial over d-range [w*32, w*32+32)
    {
        const int e = t & 63;
        float acc = 0.f;
        #pragma unroll 8
        for (int d = w * 32; d < w * 32 + 32; ++d)
            acc = fmaf(h_g[bi * DD + d], W1_g[d * EE + e], acc);
        sh_basep[w * EE + e] = acc;
    }

    // W2 B-fragments; b2 for C-init; h_d and sign-flip per d-tile
    const int dstripe = w * 32;
    short8 bfrag[2][2];
    float  nb2[2], hd2[2], flip[2];
    #pragma unroll
    for (int dt = 0; dt < 2; ++dt) {
        const int d = dstripe + 16 * dt + m16;
        nb2[dt] = b2_g[d];
        hd2[dt] = h_g[bi * DD + d];
        flip[dt] = (hd2[dt] >= 0.f) ? 1.f : -1.f;
        #pragma unroll
        for (int kh = 0; kh < 2; ++kh)
            bfrag[dt][kh] = ldb(W2_g, kh * 32 + quad * 8, d);
    }
    __syncthreads();   // barrier 1: wcnt/basep/w1e ready

    {
        int wbase = 0;
        for (int ww = 0; ww < w; ++ww) wbase += sh_wcnt[ww];
        if (mk) sh_jlist[wbase + pre] = t;
        if (t == 0) sh_cnt = sh_wcnt[0] + sh_wcnt[1] + sh_wcnt[2] + sh_wcnt[3];
    }
    if (t < EE) {
        const float base = b1_g[t] + sh_basep[t] + sh_basep[EE + t] +
                           sh_basep[2 * EE + t] + sh_basep[3 * EE + t];
        sh_q4[t * 4 + 0] = base;
        sh_q4[t * 4 + 1] = sh_w1e[t];
        sh_q4[t * 4 + 2] = sh_w1e[EE + t];
        sh_q4[t * 4 + 3] = sh_w1e[2 * EE + t];
    }
    __syncthreads();   // barrier 2: jlist/q4 ready

    // build constants: this thread's 4 {base,w1e} rows (fixed e -> stays in reg)
    f32x4 qreg[4];
    #pragma unroll
    for (int i = 0; i < 4; ++i) qreg[i] = *(const f32x4*)&sh_q4[(beb + i) * 4];

    const int cnt = sh_cnt;
    const int njt = (cnt + 15) >> 4;

    // swizzled LDS addressing (byte ^= ((row&7)<<4), bijective, b128-aligned)
    const int   sw_r = (m16 & 7) << 4;
    const char* prow = (const char*)&sh_P[0][m16 * EE];
    const int   offA = (quad * 16) ^ sw_r;        // kh=0: e 0..31
    const int   offB = (64 + quad * 16) ^ sw_r;   // kh=1: e 32..63
    char* pwr;
    {
        const int cb = 2 * beb;   // byte col of this thread's 4 e-values
        const int cs = (cb & 8) | ((((cb >> 4) ^ (bj & 7)) & 7) << 4);
        pwr = (char*)&sh_P[0][bj * EE] + cs;
    }

    float sum2[2] = {0.f, 0.f};
    float mm[2]   = {-3.0e38f, -3.0e38f};   // max over j of flip*logit

    auto buildP = [&](int jtile, int bufbyte) {
        const int row = jtile * 16 + bj;
        int jl = sh_jlist[row];
        jl = (row < cnt) ? jl : 0;              // clamp stale tail values
        const float4 efv = *(const float4*)&sh_ef4[jl * 4];
        float v[4];
        #pragma unroll
        for (int i = 0; i < 4; ++i)
            v[i] = fmaxf(fmaf(efv.z, qreg[i][3], fmaf(efv.y, qreg[i][2],
                         fmaf(efv.x, qreg[i][1], qreg[i][0]))), 0.f);
        union { __hip_bfloat162 h2; unsigned int u; } a0, a1;
        a0.h2 = __float22bfloat162_rn(make_float2(v[0], v[1]));
        a1.h2 = __float22bfloat162_rn(make_float2(v[2], v[3]));
        *reinterpret_cast<uint2*>(pwr + bufbyte) = make_uint2(a0.u, a1.u);
    };

    if (njt > 0) buildP(0, 0);
    __syncthreads();   // barrier 3: tile 0 built

    for (int jt = 0; jt < njt; ++jt) {
        const int bo = (jt & 1) << 11;          // 2048-byte buffer stride
        const short8 ua = *(const short8*)(prow + bo + offA);
        const short8 ub = *(const short8*)(prow + bo + offB);

        // build next tile into the other buffer (overlaps MFMA+epilogue)
        if (jt + 1 < njt) buildP(jt + 1, bo ^ 2048);

        const bool tail = (jt == njt - 1) && (cnt & 15);
        #pragma unroll
        for (int dt = 0; dt < 2; ++dt) {
            f32x4 acc = {nb2[dt], nb2[dt], nb2[dt], nb2[dt]};
            acc = __builtin_amdgcn_mfma_f32_16x16x32_bf16(ua, bfrag[dt][0], acc, 0, 0, 0);
            acc = __builtin_amdgcn_mfma_f32_16x16x32_bf16(ub, bfrag[dt][1], acc, 0, 0, 0);
            if (!tail) {
                #pragma unroll
                for (int r = 0; r < 4; ++r) {
                    const float l = acc[r];
                    mm[dt] = fmaxf(mm[dt], l * flip[dt]);
                    sum2[dt] += sigm(l);
                }
            } else {
                #pragma unroll
                for (int r = 0; r < 4; ++r) {
                    const bool v = (jt * 16 + quad * 4 + r) < cnt;
                    const float lx = v ? acc[r] : -3.0e38f;            // sigm -> 0
                    const float pf = v ? acc[r] * flip[dt] : -3.0e38f; // never wins max
                    mm[dt] = fmaxf(mm[dt], pf);
                    sum2[dt] += sigm(lx);
                }
            }
        }
        __syncthreads();   // next tile's buffer ready for reuse
    }

    // cross-quad reduce; sigmoid applied once on the extreme logit (monotone)
    #pragma unroll
    for (int dt = 0; dt < 2; ++dt) {
        float s = sum2[dt], M = mm[dt];
        s += __shfl_xor(s, 16, 64);  s += __shfl_xor(s, 32, 64);
        M  = fmaxf(M,  __shfl_xor(M, 16, 64));  M  = fmaxf(M,  __shfl_xor(M, 32, 64));
        if (quad == 0) {
            const int d = dstripe + 16 * dt + m16;
            const float hd = hd2[dt];
            float mean = 0.f, amax = 0.f;
            if (cnt > 0) {
                mean = hd * s * __fdividef(1.f, (float)cnt);
                amax = hd * sigm(flip[dt] * M);   // flip=+1: max l; flip=-1: min l
            }
            aggf[bi * 256 + d]       = mean;
            aggf[bi * 256 + 128 + d] = amax;
        }
    }
}

// ---------------- Kernel 2: batched update MLP + LayerNorm ----------------
// 16 rows/block, 128 blocks. B-matrices pre-packed bf16 by gate (u1t, u2t)
// in frag-major [k>>3][d][k&7] layout -> fully coalesced B loads here.
__global__ __launch_bounds__(256, 2)
void ecgc_upd(const float* __restrict__ h_g,
              const float* __restrict__ aggf,
              const unsigned short* __restrict__ u1t,
              const unsigned short* __restrict__ u2t,
              const float* __restrict__ b3_g,
              const float* __restrict__ b4_g,
              const float* __restrict__ gam_g,
              const float* __restrict__ bet_g,
              float*       __restrict__ out_g)
{
    const int bi0  = blockIdx.x * 16;
    const int t    = threadIdx.x;
    const int lane = t & 63;
    const int w    = t >> 6;
    const int m16  = lane & 15;
    const int quad = lane >> 4;

    __shared__ __align__(16) unsigned short shA[16 * APAD];
    __shared__ __align__(16) unsigned short rbuf[16 * RPAD];
    __shared__ float sh_s[4 * 16], sh_s2[4 * 16], sh_mu[16], sh_rs[16];

    {
        const int row = t >> 4, q = t & 15;
        const float* hrow = h_g  + (size_t)(bi0 + row) * DD;
        const float* wrow = aggf + (size_t)(bi0 + row) * 256;
        unsigned short tmp[24];
        #pragma unroll
        for (int c = 0; c < 24; ++c) {
            const int col = q * 24 + c;
            float v;
            if (col < 128)      v = hrow[col];
            else if (col < 256) v = wrow[col - 128];
            else                v = wrow[col - 256 + 128];
            tmp[c] = f2bf(v);
        }
        #pragma unroll
        for (int s8 = 0; s8 < 3; ++s8)
            *(short8*)&shA[row * APAD + q * 24 + s8 * 8] = *(const short8*)&tmp[s8 * 8];
    }
    __syncthreads();

    const int dstripe = w * 32;

    f32x4 acc[2];
    #pragma unroll
    for (int dt = 0; dt < 2; ++dt) {
        const float bb = b3_g[dstripe + dt * 16 + m16];
        acc[dt] = (f32x4){bb, bb, bb, bb};
    }
    for (int kk = 0; kk < 12; ++kk) {
        const short8 a0 = *(const short8*)&shA[m16 * APAD + kk * 32 + quad * 8];
        #pragma unroll
        for (int dt = 0; dt < 2; ++dt) {
            const int d = dstripe + dt * 16 + m16;
            const short8 b = *(const short8*)&u1t[(size_t)((kk * 4 + quad) * DD + d) * 8];
            acc[dt] = __builtin_amdgcn_mfma_f32_16x16x32_bf16(a0, b, acc[dt], 0, 0, 0);
        }
    }

    #pragma unroll
    for (int dt = 0; dt < 2; ++dt) {
        const int d = dstripe + dt * 16 + m16;
        #pragma unroll
        for (int r = 0; r < 4; ++r) {
            const int ro = quad * 4 + r;
            rbuf[ro * RPAD + d] = f2bf(fmaxf(acc[dt][r], 0.f));
        }
    }
    __syncthreads();

    f32x4 acc2[2];
    #pragma unroll
    for (int dt = 0; dt < 2; ++dt) {
        const float bb = b4_g[dstripe + dt * 16 + m16];
        acc2[dt] = (f32x4){bb, bb, bb, bb};
    }
    for (int kk = 0; kk < 4; ++kk) {
        const short8 a0 = *(const short8*)&rbuf[m16 * RPAD + kk * 32 + quad * 8];
        #pragma unroll
        for (int dt = 0; dt < 2; ++dt) {
            const int d = dstripe + dt * 16 + m16;
            const short8 b = *(const short8*)&u2t[(size_t)((kk * 4 + quad) * DD + d) * 8];
            acc2[dt] = __builtin_amdgcn_mfma_f32_16x16x32_bf16(a0, b, acc2[dt], 0, 0, 0);
        }
    }

    float xv[2][4];
    #pragma unroll
    for (int dt = 0; dt < 2; ++dt) {
        const int d = dstripe + dt * 16 + m16;
        #pragma unroll
        for (int r = 0; r < 4; ++r) {
            const int ro = quad * 4 + r;
            xv[dt][r] = h_g[(size_t)(bi0 + ro) * DD + d] + acc2[dt][r];
        }
    }

    #pragma unroll
    for (int r = 0; r < 4; ++r) {
        float s  = xv[0][r] + xv[1][r];
        float s2 = xv[0][r] * xv[0][r] + xv[1][r] * xv[1][r];
        #pragma unroll
        for (int off = 1; off < 16; off <<= 1) {
            s  += __shfl_xor(s,  off, 64);
            s2 += __shfl_xor(s2, off, 64);
        }
        if (m16 == 0) {
            const int ro = quad * 4 + r;
            sh_s[w * 16 + ro]  = s;
            sh_s2[w * 16 + ro] = s2;
        }
    }
    __syncthreads();
    if (t < 16) {
        const float S  = sh_s[t]  + sh_s[16 + t]  + sh_s[32 + t]  + sh_s[48 + t];
        const float S2 = sh_s2[t] + sh_s2[16 + t] + sh_s2[32 + t] + sh_s2[48 + t];
        const float mu  = S * (1.f / 128.f);
        const float var = S2 * (1.f / 128.f) - mu * mu;
        sh_mu[t] = mu;
        sh_rs[t] = rsqrtf(var + 1e-5f);
    }
    __syncthreads();

    #pragma unroll
    for (int dt = 0; dt < 2; ++dt) {
        const int d = dstripe + dt * 16 + m16;
        const float ga = gam_g[d], be = bet_g[d];
        #pragma unroll
        for (int r = 0; r < 4; ++r) {
            const int ro = quad * 4 + r;
            out_g[(size_t)(bi0 + ro) * DD + d] =
                (xv[dt][r] - sh_mu[ro]) * sh_rs[ro] * ga + be;
        }
    }
}

extern "C" void kernel_launch(void* const* d_in, const int* in_sizes, int n_in,
                              void* d_out, int out_size, void* d_ws, size_t ws_size,
                              hipStream_t stream) {
    float* aggf = (float*)d_ws;                                    // 2 MB
    unsigned short* u1t = (unsigned short*)((char*)d_ws + (size_t)2048 * 256 * 4);
    unsigned short* u2t = u1t + 384 * DD;                          // +96 KB
    ecgc_gate<<<8 * NN, 256, 0, stream>>>(
        (const float*)d_in[0],   // h
        (const float*)d_in[1],   // edge_feats
        (const int*)d_in[2],     // adj_mask
        (const float*)d_in[3],   // W1
        (const float*)d_in[4],   // b1
        (const float*)d_in[5],   // W2
        (const float*)d_in[6],   // b2
        (const float*)d_in[7],   // U1
        (const float*)d_in[9],   // U2
        aggf, u1t, u2t);
    ecgc_upd<<<(8 * NN) / 16, 256, 0, stream>>>(
        (const float*)d_in[0],   // h
        aggf, u1t, u2t,
        (const float*)d_in[8],   // b3
        (const float*)d_in[10],  // b4
        (const float*)d_in[11],  // gamma
        (const float*)d_in[12],  // beta
        (float*)d_out);
}